// Round 6
// baseline (824.987 us; speedup 1.0000x reference)
//
#include <hip/hip_runtime.h>
#include <cstdint>
#include <cstddef>

#define NN 100000
#define EE 1600000
#define HH 128
#define NB_N 391    // ceil(NN/256)
#define NBKT 391    // buckets of 256 dst nodes
#define CAP 5120    // staging capacity per bucket
#define NCH 16      // chunks per layer for rpart reduction
#define SPC 25      // ceil(NB_N/NCH)

// state slots: [0..3] radix-pick, [8] int64-layout flag, [12..14] alive counters, [16..17] edge counters

typedef float f32x2 __attribute__((ext_vector_type(2)));
typedef float f32x4 __attribute__((ext_vector_type(4)));
typedef short bf16x8 __attribute__((ext_vector_type(8)));

static __device__ __forceinline__ unsigned fsort_(float f){
  unsigned u = __float_as_uint(f);
  return (u & 0x80000000u) ? ~u : (u | 0x80000000u);
}
static __device__ __forceinline__ unsigned bfbits_(float f){
  unsigned u = __float_as_uint(f);
  return (u + 0x7FFFu + ((u >> 16) & 1u)) >> 16;
}
static __device__ __forceinline__ unsigned bfpack_(float f0, float f1){
  return bfbits_(f0) | (bfbits_(f1) << 16);
}
static __device__ __forceinline__ float bflo_(unsigned u){ return __uint_as_float(u << 16); }
static __device__ __forceinline__ float bfhi_(unsigned u){ return __uint_as_float(u & 0xFFFF0000u); }

// ---------- init: probe edge dtype + zero counters + W prep (merged) ----------
__global__ void k_init(const int* __restrict__ ei, unsigned* __restrict__ state,
                       unsigned* __restrict__ bktcnt,
                       const float* __restrict__ W0, const float* __restrict__ W1,
                       const float* __restrict__ W2,
                       unsigned short* __restrict__ WtH, unsigned short* __restrict__ WtL){
  int t = threadIdx.x;
  if(blockIdx.x == 3){
    if(t < 64){
      int v = ei[2*t + 1];
      unsigned long long m = __ballot(v != 0);
      if(t == 0) state[8] = (m == 0ull) ? 1u : 0u;
    }
    if(t >= 12 && t < 24) state[t] = 0u;
    for(int j=t; j<NBKT; j+=256) bktcnt[j] = 0u;
  } else {
    int m = blockIdx.x;
    const float* W = (m==0)?W0:((m==1)?W1:W2);
    unsigned short* th = WtH + m*16384;
    unsigned short* tl = WtL + m*16384;
    for(int i=t; i<16384; i+=256){
      int k = i & 127, n = i >> 7;
      float w = W[k*128 + n];
      unsigned hb = bfbits_(w);
      float hf = __uint_as_float(hb<<16);
      unsigned lb = bfbits_(w - hf);
      th[n*128 + k] = (unsigned short)hb;
      tl[n*128 + k] = (unsigned short)lb;
    }
  }
}

// ---------- pass A: bin edges; block-local counting sort -> coalesced staging writes ----------
__global__ __launch_bounds__(256) void k_binA(const int* __restrict__ ei,
                     const unsigned* __restrict__ state,
                     unsigned* __restrict__ bktcnt, unsigned* __restrict__ staging){
  __shared__ unsigned lcnt[NBKT];
  __shared__ unsigned gbase[NBKT];
  __shared__ unsigned lloc[NBKT];
  __shared__ unsigned pfx[512];
  __shared__ unsigned sortv[4096];
  __shared__ unsigned short bktid[4096];
  int t = threadIdx.x;
  for(int j=t; j<NBKT; j+=256){ lcnt[j] = 0u; lloc[j] = 0u; }
  bool i64 = (state[8] != 0u);
  int e0 = blockIdx.x*4096;
  int es[16], ed[16];
  #pragma unroll
  for(int k=0;k<16;k++){
    int e = e0 + k*256 + t;
    int s = -1, d = 0;
    if(e < EE){
      if(i64){ s = ei[2*e]; d = ei[2*EE + 2*e]; }
      else   { s = ei[e];   d = ei[EE + e]; }
    }
    es[k] = s; ed[k] = d;
  }
  __syncthreads();
  #pragma unroll
  for(int k=0;k<16;k++){
    if(es[k] >= 0) atomicAdd(&lcnt[ed[k]>>8], 1u);
  }
  __syncthreads();
  int j0 = t, j1 = t + 256;
  pfx[j0] = (j0 < NBKT) ? lcnt[j0] : 0u;
  pfx[j1] = (j1 < NBKT) ? lcnt[j1] : 0u;
  __syncthreads();
  for(int off=1; off<512; off<<=1){
    unsigned u0 = (j0 >= off) ? pfx[j0-off] : 0u;
    unsigned u1 = (j1 >= off) ? pfx[j1-off] : 0u;
    __syncthreads();
    pfx[j0] += u0;
    pfx[j1] += u1;
    __syncthreads();
  }
  unsigned total = pfx[NBKT-1];
  for(int j=t; j<NBKT; j+=256){
    unsigned c = lcnt[j];
    gbase[j] = c ? atomicAdd(&bktcnt[j], c) : 0u;
  }
  __syncthreads();
  #pragma unroll
  for(int k=0;k<16;k++){
    if(es[k] >= 0){
      int b = ed[k] >> 8;
      unsigned slot = (pfx[b] - lcnt[b]) + atomicAdd(&lloc[b], 1u);
      sortv[slot] = (unsigned)es[k] | (((unsigned)(ed[k] & 255)) << 17);
      bktid[slot] = (unsigned short)b;
    }
  }
  __syncthreads();
  for(unsigned i=t; i<total; i+=256){
    unsigned b = bktid[i];
    unsigned local = i - (pfx[b] - lcnt[b]);
    unsigned off = gbase[b] + local;
    if(off < CAP) staging[b*CAP + off] = sortv[i];
  }
}

// ---------- pass B: per-bucket CSR; col staged in LDS -> coalesced write ----------
__global__ __launch_bounds__(256) void k_binB(const unsigned* __restrict__ staging,
                     const unsigned* __restrict__ bktcnt,
                     int* __restrict__ rs, int* __restrict__ rl, int* __restrict__ col,
                     float* __restrict__ dinv){
  __shared__ unsigned hist[256];
  __shared__ unsigned pref[256];
  __shared__ unsigned lfill[256];
  __shared__ unsigned baseSh;
  __shared__ int colsh[CAP];
  int t = threadIdx.x;
  int b = blockIdx.x;
  unsigned s = 0;
  for(int j=t; j<b; j+=256) s += bktcnt[j];
  pref[t] = s;
  __syncthreads();
  for(int off=128; off>0; off>>=1){
    if(t < off) pref[t] += pref[t+off];
    __syncthreads();
  }
  if(t == 0) baseSh = pref[0];
  __syncthreads();
  unsigned base = baseSh;
  unsigned cnt = bktcnt[b]; if(cnt > CAP) cnt = CAP;
  hist[t] = 0u; lfill[t] = 0u;
  __syncthreads();
  const unsigned* st = staging + (unsigned)b*CAP;
  for(unsigned i=t; i<cnt; i+=256) atomicAdd(&hist[st[i]>>17], 1u);
  __syncthreads();
  unsigned h = hist[t];
  pref[t] = h;
  __syncthreads();
  for(int off=1; off<256; off<<=1){
    unsigned u = (t >= off) ? pref[t-off] : 0u;
    __syncthreads();
    pref[t] += u;
    __syncthreads();
  }
  unsigned excl = pref[t] - h;
  int node = b*256 + t;
  if(node < NN){
    rs[node] = (int)(base + excl);
    rl[node] = (int)h;
    dinv[node] = rsqrtf(1.f + (float)h);   // layer-1: all alive
  }
  __syncthreads();
  pref[t] = excl;
  __syncthreads();
  for(unsigned i=t; i<cnt; i+=256){
    unsigned w = st[i];
    unsigned dl = w >> 17;
    unsigned pos = pref[dl] + atomicAdd(&lfill[dl], 1u);   // local (< cnt)
    colsh[pos] = (int)(w & 0x1FFFFu);
  }
  __syncthreads();
  for(unsigned i=t; i<cnt; i+=256) col[base+i] = colsh[i];
}

// ---------- MFMA GEMM: y16 = bf16( scale * (X @ W) ), W pre-split bf16 hi/lo ----------
template<int MODE>
__global__ __launch_bounds__(256) void k_gemmM(const void* __restrict__ xin_,
        const float* __restrict__ gate, const float* __restrict__ dinv,
        const int* __restrict__ alist, int nrows,
        const unsigned short* __restrict__ WtH, const unsigned short* __restrict__ WtL,
        unsigned short* __restrict__ y16){
  __shared__ __attribute__((aligned(16))) unsigned short sWh[128*128];
  __shared__ __attribute__((aligned(16))) unsigned short sWl[128*128];
  __shared__ __attribute__((aligned(16))) unsigned short sB[4][16*128];
  int t = threadIdx.x;
  for(int f = t; f < 2048; f += 256){
    int colw = f >> 4, kc = f & 15;
    uint4 vh = *(const uint4*)(WtH + colw*128 + kc*8);
    uint4 vl = *(const uint4*)(WtL + colw*128 + kc*8);
    int dst = colw*128 + ((kc ^ (colw & 15)) << 3);
    *(uint4*)&sWh[dst] = vh;
    *(uint4*)&sWl[dst] = vl;
  }
  int lane = t & 63, wid = t >> 6;
  int lg = lane >> 4, lc = lane & 15;
  int rb = blockIdx.x*64 + wid*16;
  int arow = rb + lc;
  int anode = 0;
  if(arow < nrows) anode = MODE ? alist[arow] : arow;
  bf16x8 a_h[4], a_l[4];
  if(MODE){
    const unsigned short* xp = (const unsigned short*)xin_ + (size_t)anode*HH + lg*8;
    #pragma unroll
    for(int kw=0;kw<4;kw++) a_h[kw] = *(const bf16x8*)(xp + kw*32);
  } else {
    const float* xp = (const float*)xin_ + (size_t)anode*HH + lg*8;
    #pragma unroll
    for(int kw=0;kw<4;kw++){
      float4 x0 = *(const float4*)(xp + kw*32);
      float4 x1 = *(const float4*)(xp + kw*32 + 4);
      float xs[8] = {x0.x,x0.y,x0.z,x0.w,x1.x,x1.y,x1.z,x1.w};
      #pragma unroll
      for(int e=0;e<8;e++){
        unsigned hb = bfbits_(xs[e]);
        float hf = __uint_as_float(hb<<16);
        unsigned lb = bfbits_(xs[e]-hf);
        a_h[kw][e] = (short)hb;
        a_l[kw][e] = (short)lb;
      }
    }
  }
  __syncthreads();
  f32x4 acc[8];
  #pragma unroll
  for(int c=0;c<8;c++) acc[c] = (f32x4){0.f,0.f,0.f,0.f};
  #pragma unroll
  for(int kw=0;kw<4;kw++){
    int kch = kw*4 + lg;
    bf16x8 bh[8], bl[8];
    #pragma unroll
    for(int c=0;c<8;c++){
      int idx = (c*16 + lc)*128 + ((kch ^ lc) << 3);
      bh[c] = *(const bf16x8*)&sWh[idx];
      bl[c] = *(const bf16x8*)&sWl[idx];
    }
    #pragma unroll
    for(int c=0;c<8;c++)
      acc[c] = __builtin_amdgcn_mfma_f32_16x16x32_bf16(a_h[kw], bh[c], acc[c], 0,0,0);
    if(MODE){
      #pragma unroll
      for(int c=0;c<8;c++)
        acc[c] = __builtin_amdgcn_mfma_f32_16x16x32_bf16(a_h[kw], bl[c], acc[c], 0,0,0);
    } else {
      #pragma unroll
      for(int c=0;c<8;c++)
        acc[c] = __builtin_amdgcn_mfma_f32_16x16x32_bf16(a_l[kw], bh[c], acc[c], 0,0,0);
      #pragma unroll
      for(int c=0;c<8;c++)
        acc[c] = __builtin_amdgcn_mfma_f32_16x16x32_bf16(a_h[kw], bl[c], acc[c], 0,0,0);
    }
  }
  float s[4];
  #pragma unroll
  for(int r=0;r<4;r++){
    int gr = rb + lg*4 + r;
    float sv = 0.f;
    if(gr < nrows){
      int nd = MODE ? alist[gr] : gr;
      sv = MODE ? dinv[nd]*gate[nd] : dinv[nd];
    }
    s[r] = sv;
  }
  #pragma unroll
  for(int c=0;c<8;c++){
    #pragma unroll
    for(int r=0;r<4;r++)
      sB[wid][(lg*4+r)*128 + c*16 + lc] = (unsigned short)bfbits_(acc[c][r]*s[r]);
  }
  #pragma unroll
  for(int it=0; it<4; it++){
    int row = it*4 + lg;
    int grow = rb + row;
    uint4 v = *(const uint4*)&sB[wid][row*128 + lc*8];
    if(grow < nrows){
      int nd = MODE ? alist[grow] : grow;
      *(uint4*)&y16[(size_t)nd*HH + lc*8] = v;
    }
  }
}

// ---------- aggregate: feature-slab partitioned (slab = blockIdx & 7 -> XCD-local L2) ----------
// block: 16 nodes x 16 lanes; per node: 4 edge-groups x 4 col-lanes (uint2 = 4 bf16 cols).
// writes h16 slab (disjoint) + per-slab score partial p8[node][slab] (no atomics).
template<int LIST>
__global__ __launch_bounds__(256) void k_agg(const unsigned short* __restrict__ y16,
        const float* __restrict__ dinv,
        const int* __restrict__ rs, const int* __restrict__ rl,
        const int* __restrict__ col, const int* __restrict__ alist,
        const float* __restrict__ bias, const float* __restrict__ wsc,
        unsigned short* __restrict__ h16, float* __restrict__ p8,
        unsigned* __restrict__ hist, int n){
  if(blockIdx.x < 512) hist[blockIdx.x*256 + threadIdx.x] = 0u;
  int slab = blockIdx.x & 7;
  int w = ((blockIdx.x >> 3) << 4) + (threadIdx.x >> 4);
  int nl = threadIdx.x & 15;
  int g = nl >> 2, c = nl & 3;
  bool act = (w < n);
  int node = 0;
  if(act) node = LIST ? alist[w] : w;
  float di = act ? dinv[node] : 0.f;
  int e0 = 0, len = 0;
  if(act){ e0 = rs[node]; len = rl[node]; }
  const char* yb = (const char*)y16;
  unsigned off8 = ((unsigned)slab << 5) | ((unsigned)c << 3);
  float a0=0.f, a1=0.f, a2=0.f, a3=0.f;
  const int* ce = col + e0;
  int i = g;
  for(; i + 4 < len; i += 8){
    int s0 = ce[i], s1 = ce[i+4];
    uint2 v0 = *(const uint2*)(yb + (((unsigned)s0<<8) | off8));
    uint2 v1 = *(const uint2*)(yb + (((unsigned)s1<<8) | off8));
    a0 += bflo_(v0.x) + bflo_(v1.x);
    a1 += bfhi_(v0.x) + bfhi_(v1.x);
    a2 += bflo_(v0.y) + bflo_(v1.y);
    a3 += bfhi_(v0.y) + bfhi_(v1.y);
  }
  if(i < len){
    int s0 = ce[i];
    uint2 v0 = *(const uint2*)(yb + (((unsigned)s0<<8) | off8));
    a0 += bflo_(v0.x); a1 += bfhi_(v0.x);
    a2 += bflo_(v0.y); a3 += bfhi_(v0.y);
  }
  // reduce over the 4 edge-groups (xor 4, 8 stays within the 16-lane node group)
  a0 += __shfl_xor(a0,4,64); a0 += __shfl_xor(a0,8,64);
  a1 += __shfl_xor(a1,4,64); a1 += __shfl_xor(a1,8,64);
  a2 += __shfl_xor(a2,4,64); a2 += __shfl_xor(a2,8,64);
  a3 += __shfl_xor(a3,4,64); a3 += __shfl_xor(a3,8,64);
  uint2 sv = make_uint2(0u,0u);
  if(act) sv = *(const uint2*)(yb + (((unsigned)node<<8) | off8));  // self row, prescaled
  float4 bb = ((const float4*)bias)[slab*4 + c];
  float4 wv = ((const float4*)wsc)[slab*4 + c];
  float o0 = fmaxf(fmaf(di, a0 + bflo_(sv.x), bb.x), 0.f);
  float o1 = fmaxf(fmaf(di, a1 + bfhi_(sv.x), bb.y), 0.f);
  float o2 = fmaxf(fmaf(di, a2 + bflo_(sv.y), bb.z), 0.f);
  float o3 = fmaxf(fmaf(di, a3 + bfhi_(sv.y), bb.w), 0.f);
  if(g == 0 && act){
    uint2 o;
    o.x = bfpack_(o0,o1); o.y = bfpack_(o2,o3);
    *(uint2*)&h16[(size_t)node*HH + slab*16 + c*4] = o;
  }
  float pp = o0*wv.x + o1*wv.y + o2*wv.z + o3*wv.w;
  pp += __shfl_xor(pp, 1, 64);
  pp += __shfl_xor(pp, 2, 64);
  if(nl == 0 && act) p8[(size_t)node*8 + slab] = di*pp;
}

// ---------- deterministic reduce of p8 slab partials ----------
template<int LIST>
__global__ void k_psum(const float* __restrict__ p8, const int* __restrict__ alist, int n,
                       float* __restrict__ p){
  int w = blockIdx.x*256 + threadIdx.x;
  if(w >= n) return;
  int i = LIST ? alist[w] : w;
  const float4* q = (const float4*)(p8 + (size_t)i*8);
  float4 u = q[0], v = q[1];
  p[i] = ((u.x+u.y)+(u.z+u.w)) + ((v.x+v.y)+(v.z+v.w));
}

// ---------- score + fused hi-histogram ----------
template<int LIST>
__global__ void k_score(const float* __restrict__ p, const float* __restrict__ dinv,
                        const int* __restrict__ rs, const int* __restrict__ rl,
                        const int* __restrict__ col, const int* __restrict__ alist, int n,
                        const float* __restrict__ bs, float* __restrict__ score,
                        unsigned* __restrict__ key, unsigned* __restrict__ hist){
  int w = blockIdx.x*256 + threadIdx.x;
  if(w >= n) return;
  int i = LIST ? alist[w] : w;
  float di = dinv[i];
  float s = 0.f;
  int e0 = rs[i], len = rl[i];
  const int* ce = col + e0;
  int e = 0;
  for(; e+3 < len; e += 4){
    int c0 = ce[e], c1 = ce[e+1], c2 = ce[e+2], c3 = ce[e+3];
    s += (p[c0] + p[c1]) + (p[c2] + p[c3]);
  }
  for(; e < len; e++) s += p[ce[e]];
  float sc = di*(s + p[i]) + bs[0];
  score[i] = sc;
  unsigned kv = fsort_(sc);
  key[i] = kv;
  atomicAdd(&hist[kv>>16], 1u);
}

// ---------- radix select ----------
__global__ void k_hist_lo(const unsigned* __restrict__ key, const unsigned* __restrict__ state,
                          unsigned* __restrict__ histB){
  int i = blockIdx.x*256 + threadIdx.x;
  if(i < NN){
    unsigned kv = key[i];
    if((kv >> 16) == state[0]) atomicAdd(&histB[kv & 0xFFFFu], 1u);
  }
}
__global__ void k_pick(const unsigned* __restrict__ hist, unsigned* __restrict__ state,
                       int k_in, int mode){
  __shared__ unsigned csum[256];
  __shared__ unsigned vrow[256];
  __shared__ int rowSh;
  __shared__ unsigned aboveSh;
  int t = threadIdx.x;
  const uint4* h4 = (const uint4*)(hist + t*256);
  unsigned s = 0;
  for(int j=0;j<64;j++){ uint4 v = h4[j]; s += v.x+v.y+v.z+v.w; }
  csum[t] = s;
  if(t == 0) rowSh = -1;
  __syncthreads();
  for(int off=1; off<256; off<<=1){
    unsigned v = (t+off < 256) ? csum[t+off] : 0u;
    __syncthreads();
    csum[t] += v;
    __syncthreads();
  }
  unsigned k = (mode == 0) ? (unsigned)k_in : state[1];
  unsigned above = csum[t] - s;
  if(above < k && above + s >= k){ rowSh = t; aboveSh = above; }
  __syncthreads();
  int row = rowSh;
  if(row >= 0){
    vrow[t] = hist[row*256 + t];
    __syncthreads();
    for(int off=1; off<256; off<<=1){
      unsigned u = (t+off < 256) ? vrow[t+off] : 0u;
      __syncthreads();
      vrow[t] += u;
      __syncthreads();
    }
    // vrow[t] = suffix-inclusive sum; find largest j with above + suffixIncl(j) >= k
    unsigned above2 = aboveSh;
    unsigned sincl = vrow[t];
    unsigned snext = (t < 255) ? vrow[t+1] : 0u;
    bool cond  = (above2 + sincl >= k);
    bool condn = (above2 + snext >= k);
    if(cond && !condn){
      unsigned run = above2 + snext;
      if(mode == 0){ state[0] = (unsigned)(row*256+t); state[1] = k - run; }
      else { state[2] = (state[0] << 16) | (unsigned)(row*256+t); state[3] = k - run; }
    }
  }
}

// ---------- mask + gate + alive-list + select-bitmask + fused readout partials ----------
__global__ __launch_bounds__(256) void k_maskCR(unsigned* __restrict__ key,
        const float* __restrict__ score, const unsigned* __restrict__ state,
        const unsigned short* __restrict__ h16,
        unsigned* __restrict__ selb, float* __restrict__ gate,
        int* __restrict__ alist_out, unsigned* __restrict__ acounter,
        float* __restrict__ rpart, int slotbase){
  __shared__ int wcnt[4];
  __shared__ int priorSh;
  __shared__ int redi[256];
  __shared__ float gl[256];
  __shared__ unsigned char slf[256];
  __shared__ float4 red[256];
  __shared__ float out2[256];
  int t = threadIdx.x;
  int i = blockIdx.x*256 + t;
  unsigned T = state[2];
  int trem = (int)state[3];
  unsigned kv = (i < NN) ? key[i] : 0u;
  bool match = (kv == T);
  unsigned long long m = __ballot(match);
  int lane = t & 63, wid = t >> 6;
  if(lane == 0) wcnt[wid] = __popcll(m);
  if(t == 0) priorSh = 0;
  __syncthreads();
  int hasMatch = wcnt[0] | wcnt[1] | wcnt[2] | wcnt[3];
  int bbase = blockIdx.x*256;
  if(hasMatch){
    int cm = 0;
    for(int j = t*4; j < bbase; j += 1024){
      uint4 kk = *(const uint4*)&key[j];
      cm += (kk.x==T) + (kk.y==T) + (kk.z==T) + (kk.w==T);
    }
    redi[t] = cm;
    __syncthreads();
    for(int off=128; off>0; off>>=1){
      if(t < off) redi[t] += redi[t+off];
      __syncthreads();
    }
    if(t == 0) priorSh = redi[0];
    __syncthreads();
  }
  int pre = 0;
  for(int w=0; w<wid; w++) pre += wcnt[w];
  int lrank = __popcll(m & ((1ull << lane) - 1ull));
  int rank = priorSh + pre + lrank;
  bool sel = (kv > T) || (match && rank < trem);
  float gg = sel ? tanhf(score[i]) : 0.f;
  gl[t] = gg;
  slf[t] = sel ? 1 : 0;
  if(i < NN){
    gate[i] = gg;
    if(!sel) key[i] = 0u;
  }
  unsigned long long sm = __ballot(sel);
  if(lane == 0){
    int widx = blockIdx.x*4 + wid;
    selb[widx*2]   = (unsigned)sm;
    selb[widx*2+1] = (unsigned)(sm >> 32);
  }
  unsigned abase = 0;
  if(lane == 0) abase = atomicAdd(acounter, (unsigned)__popcll(sm));
  abase = (unsigned)__shfl((int)abase, 0, 64);
  if(sel) alist_out[abase + __popcll(sm & ((1ull << lane) - 1ull))] = i;
  __syncthreads();
  int ch = t & 15;
  int slot = t >> 4;
  float mm[8] = {0,0,0,0,0,0,0,0};
  float MM[8] = {-1e30f,-1e30f,-1e30f,-1e30f,-1e30f,-1e30f,-1e30f,-1e30f};
  for(int itr=0; itr<16; itr++){
    int nl = slot + itr*16;
    int node = bbase + nl;
    if(node < NN && slf[nl]){
      float g = gl[nl];
      uint4 v = ((const uint4*)(h16 + (size_t)node*HH))[ch];
      float x0 = g*bflo_(v.x), x1 = g*bfhi_(v.x);
      float x2 = g*bflo_(v.y), x3 = g*bfhi_(v.y);
      float x4 = g*bflo_(v.z), x5 = g*bfhi_(v.z);
      float x6 = g*bflo_(v.w), x7 = g*bfhi_(v.w);
      mm[0]+=x0; mm[1]+=x1; mm[2]+=x2; mm[3]+=x3;
      mm[4]+=x4; mm[5]+=x5; mm[6]+=x6; mm[7]+=x7;
      MM[0]=fmaxf(MM[0],x0); MM[1]=fmaxf(MM[1],x1); MM[2]=fmaxf(MM[2],x2); MM[3]=fmaxf(MM[3],x3);
      MM[4]=fmaxf(MM[4],x4); MM[5]=fmaxf(MM[5],x5); MM[6]=fmaxf(MM[6],x6); MM[7]=fmaxf(MM[7],x7);
    }
  }
  #pragma unroll
  for(int half=0; half<2; half++){
    red[t] = make_float4(mm[half*4+0],mm[half*4+1],mm[half*4+2],mm[half*4+3]);
    __syncthreads();
    if(t < 16){
      float4 sacc = red[t];
      for(int j=1;j<16;j++){
        float4 o = red[t + 16*j];
        sacc.x += o.x; sacc.y += o.y; sacc.z += o.z; sacc.w += o.w;
      }
      int d = t*8 + half*4;
      out2[d+0] = sacc.x; out2[d+1] = sacc.y; out2[d+2] = sacc.z; out2[d+3] = sacc.w;
    }
    __syncthreads();
    red[t] = make_float4(MM[half*4+0],MM[half*4+1],MM[half*4+2],MM[half*4+3]);
    __syncthreads();
    if(t < 16){
      float4 sacc = red[t];
      for(int j=1;j<16;j++){
        float4 o = red[t + 16*j];
        sacc.x = fmaxf(sacc.x,o.x); sacc.y = fmaxf(sacc.y,o.y);
        sacc.z = fmaxf(sacc.z,o.z); sacc.w = fmaxf(sacc.w,o.w);
      }
      int d = 128 + t*8 + half*4;
      out2[d+0] = sacc.x; out2[d+1] = sacc.y; out2[d+2] = sacc.z; out2[d+3] = sacc.w;
    }
    __syncthreads();
  }
  rpart[(size_t)(slotbase + blockIdx.x)*256 + t] = out2[t];
}

// ---------- parallel edge compaction: bitmask select, 16 lanes/node ----------
__global__ __launch_bounds__(256) void k_compact(const int* __restrict__ alist, int n,
        const unsigned* __restrict__ selb,
        const int* __restrict__ rs_old, const int* __restrict__ rl_old,
        const int* __restrict__ col_old,
        int* __restrict__ rs_new, int* __restrict__ rl_new, int* __restrict__ col_new,
        float* __restrict__ dinv, unsigned* __restrict__ ecnt){
  __shared__ unsigned gcnt[16];
  __shared__ unsigned gbase[16];
  __shared__ unsigned blkbase;
  int t = threadIdx.x;
  int g = t >> 4, lane = t & 15;
  int gsh = ((t >> 4) & 3) * 16;
  int idx = blockIdx.x*16 + g;
  int node = -1, e0 = 0, len = 0;
  if(idx < n){ node = alist[idx]; e0 = rs_old[node]; len = rl_old[node]; }
  int cnt = 0;
  for(int i=lane; i<len; i+=16){
    int s = col_old[e0+i];
    cnt += (int)((selb[s>>5] >> (s&31)) & 1u);
  }
  cnt += __shfl_xor(cnt,1,64); cnt += __shfl_xor(cnt,2,64);
  cnt += __shfl_xor(cnt,4,64); cnt += __shfl_xor(cnt,8,64);
  if(lane == 0) gcnt[g] = (node >= 0) ? (unsigned)cnt : 0u;
  __syncthreads();
  if(t == 0){
    unsigned s = 0;
    for(int j=0;j<16;j++){ gbase[j] = s; s += gcnt[j]; }
    blkbase = s ? atomicAdd(ecnt, s) : 0u;
  }
  __syncthreads();
  unsigned base = blkbase + gbase[g];
  if(node >= 0 && lane == 0){
    rs_new[node] = (int)base;
    rl_new[node] = cnt;
    dinv[node] = rsqrtf(1.f + (float)cnt);
  }
  int pos = (int)base;
  for(int i0=0; i0<len; i0+=16){
    int i = i0 + lane;
    bool keep = false; int s = 0;
    if(i < len){ s = col_old[e0+i]; keep = ((selb[s>>5] >> (s&31)) & 1u) != 0u; }
    unsigned long long b = __ballot(keep);
    unsigned gb = (unsigned)((b >> gsh) & 0xFFFFull);
    int rank = __popc(gb & ((1u << lane) - 1u));
    if(keep) col_new[pos + rank] = s;
    pos += __popc(gb);
  }
}

// ---------- parallel reduce of readout partials: 48 blocks ----------
__global__ void k_red(const float* __restrict__ rpart, float* __restrict__ rpart2){
  int l = blockIdx.x >> 4, c = blockIdx.x & 15;
  int t = threadIdx.x;
  int j0 = c*SPC, j1 = j0 + SPC; if(j1 > NB_N) j1 = NB_N;
  const float* rp = rpart + (size_t)l*NB_N*256;
  float r;
  if(t < 128){
    float s0=0.f,s1=0.f,s2=0.f,s3=0.f;
    int j = j0;
    for(; j+3 < j1; j += 4){
      s0 += rp[(size_t)(j  )*256 + t];
      s1 += rp[(size_t)(j+1)*256 + t];
      s2 += rp[(size_t)(j+2)*256 + t];
      s3 += rp[(size_t)(j+3)*256 + t];
    }
    for(; j < j1; j++) s0 += rp[(size_t)j*256 + t];
    r = (s0+s1)+(s2+s3);
  } else {
    float m0=-1e30f,m1=-1e30f,m2=-1e30f,m3=-1e30f;
    int j = j0;
    for(; j+3 < j1; j += 4){
      m0 = fmaxf(m0, rp[(size_t)(j  )*256 + t]);
      m1 = fmaxf(m1, rp[(size_t)(j+1)*256 + t]);
      m2 = fmaxf(m2, rp[(size_t)(j+2)*256 + t]);
      m3 = fmaxf(m3, rp[(size_t)(j+3)*256 + t]);
    }
    for(; j < j1; j++) m0 = fmaxf(m0, rp[(size_t)j*256 + t]);
    r = fmaxf(fmaxf(m0,m1), fmaxf(m2,m3));
  }
  rpart2[(size_t)blockIdx.x*256 + t] = r;
}

// ---------- final reduce (48 chunk-partials) + MLP head + log_softmax ----------
__global__ void k_mlp(const float* __restrict__ rpart2,
                      const float* __restrict__ M1, const float* __restrict__ bm1,
                      const float* __restrict__ M2, const float* __restrict__ bm2,
                      const float* __restrict__ M3, const float* __restrict__ bm3,
                      float* __restrict__ out){
  __shared__ float R[256];
  __shared__ float y1[128];
  __shared__ float y2[64];
  __shared__ float y3[16];
  int t = threadIdx.x;
  const float kinv[3] = {1.f/50000.f, 1.f/25000.f, 1.f/12500.f};
  if(t < 128){
    float acc = 0.f;
    for(int l=0; l<3; l++){
      float s = 0.f;
      #pragma unroll
      for(int c=0; c<NCH; c++) s += rpart2[(size_t)(l*NCH+c)*256 + t];
      acc += s * kinv[l];
    }
    R[t] = acc;
  } else {
    float acc = 0.f;
    for(int l=0; l<3; l++){
      float m = -1e30f;
      #pragma unroll
      for(int c=0; c<NCH; c++) m = fmaxf(m, rpart2[(size_t)(l*NCH+c)*256 + t]);
      acc += m;
    }
    R[t] = acc;
  }
  __syncthreads();
  if(t < 128){
    float a = bm1[t];
    for(int d=0; d<256; d++) a += R[d]*M1[d*128+t];
    y1[t] = fmaxf(a, 0.f);
  }
  __syncthreads();
  if(t < 64){
    float a = bm2[t];
    for(int d=0; d<128; d++) a += y1[d]*M2[d*64+t];
    y2[t] = fmaxf(a, 0.f);
  }
  __syncthreads();
  if(t < 10){
    float a = bm3[t];
    for(int d=0; d<64; d++) a += y2[d]*M3[d*10+t];
    y3[t] = a;
  }
  __syncthreads();
  if(t == 0){
    float mx = -1e30f;
    for(int o=0;o<10;o++) mx = fmaxf(mx, y3[o]);
    float s = 0.f;
    for(int o=0;o<10;o++) s += expf(y3[o]-mx);
    float ls = logf(s);
    for(int o=0;o<10;o++) out[o] = y3[o] - mx - ls;
  }
}

extern "C" void kernel_launch(void* const* d_in, const int* in_sizes, int n_in,
                              void* d_out, int out_size, void* d_ws, size_t ws_size,
                              hipStream_t stream){
  (void)in_sizes; (void)n_in; (void)out_size; (void)ws_size;
  const float* x  = (const float*)d_in[0];
  const int*   ei = (const int*)d_in[1];
  const float* W[3]   = {(const float*)d_in[2],  (const float*)d_in[6],  (const float*)d_in[10]};
  const float* bb[3]  = {(const float*)d_in[3],  (const float*)d_in[7],  (const float*)d_in[11]};
  const float* wsc[3] = {(const float*)d_in[4],  (const float*)d_in[8],  (const float*)d_in[12]};
  const float* bsc[3] = {(const float*)d_in[5],  (const float*)d_in[9],  (const float*)d_in[13]};
  const float* M1  = (const float*)d_in[14];
  const float* bm1 = (const float*)d_in[15];
  const float* M2  = (const float*)d_in[16];
  const float* bm2 = (const float*)d_in[17];
  const float* M3  = (const float*)d_in[18];
  const float* bm3 = (const float*)d_in[19];
  float* out = (float*)d_out;

  char* base = (char*)d_ws;
  size_t off = 0;
  auto alloc = [&](size_t bytes)->char*{
    char* ptr = base + off;
    off += (bytes + 511) & ~(size_t)511;
    return ptr;
  };
  unsigned short* y16  = (unsigned short*)alloc((size_t)NN*HH*2);
  unsigned short* h16  = (unsigned short*)alloc((size_t)NN*HH*2);
  int*      col0      = (int*)     alloc((size_t)EE*4);
  int*      col1      = (int*)     alloc((size_t)EE*4);
  int*      col2      = (int*)     alloc((size_t)EE*4);
  unsigned* staging   = (unsigned*)alloc((size_t)NBKT*CAP*4);
  int*      rs0       = (int*)     alloc((size_t)NN*4);
  int*      rl0       = (int*)     alloc((size_t)NN*4);
  int*      rs1       = (int*)     alloc((size_t)NN*4);
  int*      rl1       = (int*)     alloc((size_t)NN*4);
  int*      rs2       = (int*)     alloc((size_t)NN*4);
  int*      rl2       = (int*)     alloc((size_t)NN*4);
  float*    dinv      = (float*)   alloc((size_t)NN*4);
  float*    pbuf      = (float*)   alloc((size_t)NN*4);
  float*    p8        = (float*)   alloc((size_t)NN*8*4);
  float*    score     = (float*)   alloc((size_t)NN*4);
  float*    gate      = (float*)   alloc((size_t)NN*4);
  unsigned* key       = (unsigned*)alloc((size_t)NN*4);
  unsigned* selb      = (unsigned*)alloc((size_t)3200*4);
  int*      alistA    = (int*)     alloc((size_t)50000*4);
  int*      alistB    = (int*)     alloc((size_t)25000*4);
  unsigned* hist      = (unsigned*)alloc((size_t)2*65536*4);
  unsigned* bktcnt    = (unsigned*)alloc((size_t)(NBKT+1)*4);
  unsigned* state     = (unsigned*)alloc(256);
  float*    rpart     = (float*)   alloc((size_t)3*NB_N*256*4);
  float*    rpart2    = (float*)   alloc((size_t)3*NCH*256*4);
  unsigned short* WtH = (unsigned short*)alloc((size_t)3*16384*2);
  unsigned short* WtL = (unsigned short*)alloc((size_t)3*16384*2);

  // CSR build + W prep
  k_init<<<4,256,0,stream>>>(ei, state, bktcnt, W[0], W[1], W[2], WtH, WtL);
  k_binA<<<NBKT,256,0,stream>>>(ei, state, bktcnt, staging);
  k_binB<<<NBKT,256,0,stream>>>(staging, bktcnt, rs0, rl0, col0, dinv);

  // ---- layer 1 (identity rows: all 100000 alive) ----
  k_gemmM<0><<<1563,256,0,stream>>>(x, nullptr, dinv, nullptr, NN, WtH, WtL, y16);
  k_agg<0><<<50000,256,0,stream>>>(y16, dinv, rs0, rl0, col0, nullptr, bb[0], wsc[0], h16, p8, hist, NN);
  k_psum<0><<<NB_N,256,0,stream>>>(p8, nullptr, NN, pbuf);
  k_score<0><<<NB_N,256,0,stream>>>(pbuf, dinv, rs0, rl0, col0, nullptr, NN, bsc[0], score, key, hist);
  k_pick<<<1,256,0,stream>>>(hist, state, 50000, 0);
  k_hist_lo<<<NB_N,256,0,stream>>>(key, state, hist + 65536);
  k_pick<<<1,256,0,stream>>>(hist + 65536, state, 0, 1);
  k_maskCR<<<NB_N,256,0,stream>>>(key, score, state, h16, selb, gate, alistA, state+12, rpart, 0);
  k_compact<<<3125,256,0,stream>>>(alistA, 50000, selb, rs0, rl0, col0, rs1, rl1, col1, dinv, state+16);

  // ---- layer 2 (50000 alive) ----
  k_gemmM<1><<<782,256,0,stream>>>(h16, gate, dinv, alistA, 50000, WtH+16384, WtL+16384, y16);
  k_agg<1><<<25000,256,0,stream>>>(y16, dinv, rs1, rl1, col1, alistA, bb[1], wsc[1], h16, p8, hist, 50000);
  k_psum<1><<<196,256,0,stream>>>(p8, alistA, 50000, pbuf);
  k_score<1><<<196,256,0,stream>>>(pbuf, dinv, rs1, rl1, col1, alistA, 50000, bsc[1], score, key, hist);
  k_pick<<<1,256,0,stream>>>(hist, state, 25000, 0);
  k_hist_lo<<<NB_N,256,0,stream>>>(key, state, hist + 65536);
  k_pick<<<1,256,0,stream>>>(hist + 65536, state, 0, 1);
  k_maskCR<<<NB_N,256,0,stream>>>(key, score, state, h16, selb, gate, alistB, state+13, rpart, NB_N);
  k_compact<<<1563,256,0,stream>>>(alistB, 25000, selb, rs1, rl1, col1, rs2, rl2, col2, dinv, state+17);

  // ---- layer 3 (25000 alive) ----
  k_gemmM<1><<<391,256,0,stream>>>(h16, gate, dinv, alistB, 25000, WtH+2*16384, WtL+2*16384, y16);
  k_agg<1><<<12504,256,0,stream>>>(y16, dinv, rs2, rl2, col2, alistB, bb[2], wsc[2], h16, p8, hist, 25000);
  k_psum<1><<<98,256,0,stream>>>(p8, alistB, 25000, pbuf);
  k_score<1><<<98,256,0,stream>>>(pbuf, dinv, rs2, rl2, col2, alistB, 25000, bsc[2], score, key, hist);
  k_pick<<<1,256,0,stream>>>(hist, state, 12500, 0);
  k_hist_lo<<<NB_N,256,0,stream>>>(key, state, hist + 65536);
  k_pick<<<1,256,0,stream>>>(hist + 65536, state, 0, 1);
  k_maskCR<<<NB_N,256,0,stream>>>(key, score, state, h16, selb, gate, alistA, state+14, rpart, 2*NB_N);

  k_red<<<3*NCH,256,0,stream>>>(rpart, rpart2);
  k_mlp<<<1,256,0,stream>>>(rpart2, M1, bm1, M2, bm2, M3, bm3, out);
}

// Round 7
// 640.087 us; speedup vs baseline: 1.2889x; 1.2889x over previous
//
#include <hip/hip_runtime.h>
#include <cstdint>
#include <cstddef>

#define NN 100000
#define EE 1600000
#define HH 128
#define NB_N 391    // ceil(NN/256)
#define NBKT 391    // buckets of 256 dst nodes
#define CAP 5120    // staging capacity per bucket
#define NCH 16      // chunks per layer for rpart reduction
#define SPC 25      // ceil(NB_N/NCH)

// state slots: [0..3] radix-pick, [8] int64-layout flag, [12..14] alive counters, [16..17] edge counters

typedef float f32x2 __attribute__((ext_vector_type(2)));
typedef float f32x4 __attribute__((ext_vector_type(4)));
typedef short bf16x8 __attribute__((ext_vector_type(8)));

static __device__ __forceinline__ unsigned fsort_(float f){
  unsigned u = __float_as_uint(f);
  return (u & 0x80000000u) ? ~u : (u | 0x80000000u);
}
static __device__ __forceinline__ unsigned bfbits_(float f){
  unsigned u = __float_as_uint(f);
  return (u + 0x7FFFu + ((u >> 16) & 1u)) >> 16;
}
static __device__ __forceinline__ unsigned bfpack_(float f0, float f1){
  return bfbits_(f0) | (bfbits_(f1) << 16);
}
static __device__ __forceinline__ float bflo_(unsigned u){ return __uint_as_float(u << 16); }
static __device__ __forceinline__ float bfhi_(unsigned u){ return __uint_as_float(u & 0xFFFF0000u); }

// ---------- init: probe edge dtype + zero counters + W prep (merged) ----------
__global__ void k_init(const int* __restrict__ ei, unsigned* __restrict__ state,
                       unsigned* __restrict__ bktcnt,
                       const float* __restrict__ W0, const float* __restrict__ W1,
                       const float* __restrict__ W2,
                       unsigned short* __restrict__ WtH, unsigned short* __restrict__ WtL){
  int t = threadIdx.x;
  if(blockIdx.x == 3){
    if(t < 64){
      int v = ei[2*t + 1];
      unsigned long long m = __ballot(v != 0);
      if(t == 0) state[8] = (m == 0ull) ? 1u : 0u;
    }
    if(t >= 12 && t < 24) state[t] = 0u;
    for(int j=t; j<NBKT; j+=256) bktcnt[j] = 0u;
  } else {
    int m = blockIdx.x;
    const float* W = (m==0)?W0:((m==1)?W1:W2);
    unsigned short* th = WtH + m*16384;
    unsigned short* tl = WtL + m*16384;
    for(int i=t; i<16384; i+=256){
      int k = i & 127, n = i >> 7;
      float w = W[k*128 + n];
      unsigned hb = bfbits_(w);
      float hf = __uint_as_float(hb<<16);
      unsigned lb = bfbits_(w - hf);
      th[n*128 + k] = (unsigned short)hb;
      tl[n*128 + k] = (unsigned short)lb;
    }
  }
}

// ---------- pass A: bin edges; block-local counting sort -> coalesced staging writes ----------
__global__ __launch_bounds__(256) void k_binA(const int* __restrict__ ei,
                     const unsigned* __restrict__ state,
                     unsigned* __restrict__ bktcnt, unsigned* __restrict__ staging){
  __shared__ unsigned lcnt[NBKT];
  __shared__ unsigned gbase[NBKT];
  __shared__ unsigned lloc[NBKT];
  __shared__ unsigned pfx[512];
  __shared__ unsigned sortv[4096];
  __shared__ unsigned short bktid[4096];
  int t = threadIdx.x;
  for(int j=t; j<NBKT; j+=256){ lcnt[j] = 0u; lloc[j] = 0u; }
  bool i64 = (state[8] != 0u);
  int e0 = blockIdx.x*4096;
  int es[16], ed[16];
  #pragma unroll
  for(int k=0;k<16;k++){
    int e = e0 + k*256 + t;
    int s = -1, d = 0;
    if(e < EE){
      if(i64){ s = ei[2*e]; d = ei[2*EE + 2*e]; }
      else   { s = ei[e];   d = ei[EE + e]; }
    }
    es[k] = s; ed[k] = d;
  }
  __syncthreads();
  #pragma unroll
  for(int k=0;k<16;k++){
    if(es[k] >= 0) atomicAdd(&lcnt[ed[k]>>8], 1u);
  }
  __syncthreads();
  int j0 = t, j1 = t + 256;
  pfx[j0] = (j0 < NBKT) ? lcnt[j0] : 0u;
  pfx[j1] = (j1 < NBKT) ? lcnt[j1] : 0u;
  __syncthreads();
  for(int off=1; off<512; off<<=1){
    unsigned u0 = (j0 >= off) ? pfx[j0-off] : 0u;
    unsigned u1 = (j1 >= off) ? pfx[j1-off] : 0u;
    __syncthreads();
    pfx[j0] += u0;
    pfx[j1] += u1;
    __syncthreads();
  }
  unsigned total = pfx[NBKT-1];
  for(int j=t; j<NBKT; j+=256){
    unsigned c = lcnt[j];
    gbase[j] = c ? atomicAdd(&bktcnt[j], c) : 0u;
  }
  __syncthreads();
  #pragma unroll
  for(int k=0;k<16;k++){
    if(es[k] >= 0){
      int b = ed[k] >> 8;
      unsigned slot = (pfx[b] - lcnt[b]) + atomicAdd(&lloc[b], 1u);
      sortv[slot] = (unsigned)es[k] | (((unsigned)(ed[k] & 255)) << 17);
      bktid[slot] = (unsigned short)b;
    }
  }
  __syncthreads();
  for(unsigned i=t; i<total; i+=256){
    unsigned b = bktid[i];
    unsigned local = i - (pfx[b] - lcnt[b]);
    unsigned off = gbase[b] + local;
    if(off < CAP) staging[b*CAP + off] = sortv[i];
  }
}

// ---------- pass B: per-bucket CSR; col staged in LDS -> coalesced write ----------
__global__ __launch_bounds__(256) void k_binB(const unsigned* __restrict__ staging,
                     const unsigned* __restrict__ bktcnt,
                     int* __restrict__ rs, int* __restrict__ rl, int* __restrict__ col,
                     float* __restrict__ dinv){
  __shared__ unsigned hist[256];
  __shared__ unsigned pref[256];
  __shared__ unsigned lfill[256];
  __shared__ unsigned baseSh;
  __shared__ int colsh[CAP];
  int t = threadIdx.x;
  int b = blockIdx.x;
  unsigned s = 0;
  for(int j=t; j<b; j+=256) s += bktcnt[j];
  pref[t] = s;
  __syncthreads();
  for(int off=128; off>0; off>>=1){
    if(t < off) pref[t] += pref[t+off];
    __syncthreads();
  }
  if(t == 0) baseSh = pref[0];
  __syncthreads();
  unsigned base = baseSh;
  unsigned cnt = bktcnt[b]; if(cnt > CAP) cnt = CAP;
  hist[t] = 0u; lfill[t] = 0u;
  __syncthreads();
  const unsigned* st = staging + (unsigned)b*CAP;
  for(unsigned i=t; i<cnt; i+=256) atomicAdd(&hist[st[i]>>17], 1u);
  __syncthreads();
  unsigned h = hist[t];
  pref[t] = h;
  __syncthreads();
  for(int off=1; off<256; off<<=1){
    unsigned u = (t >= off) ? pref[t-off] : 0u;
    __syncthreads();
    pref[t] += u;
    __syncthreads();
  }
  unsigned excl = pref[t] - h;
  int node = b*256 + t;
  if(node < NN){
    rs[node] = (int)(base + excl);
    rl[node] = (int)h;
    dinv[node] = rsqrtf(1.f + (float)h);   // layer-1: all alive
  }
  __syncthreads();
  pref[t] = excl;
  __syncthreads();
  for(unsigned i=t; i<cnt; i+=256){
    unsigned w = st[i];
    unsigned dl = w >> 17;
    unsigned pos = pref[dl] + atomicAdd(&lfill[dl], 1u);   // local (< cnt)
    colsh[pos] = (int)(w & 0x1FFFFu);
  }
  __syncthreads();
  for(unsigned i=t; i<cnt; i+=256) col[base+i] = colsh[i];
}

// ---------- MFMA GEMM: y16 = bf16( scale * (X @ W) ), W pre-split bf16 hi/lo ----------
template<int MODE>
__global__ __launch_bounds__(256) void k_gemmM(const void* __restrict__ xin_,
        const float* __restrict__ gate, const float* __restrict__ dinv,
        const int* __restrict__ alist, int nrows,
        const unsigned short* __restrict__ WtH, const unsigned short* __restrict__ WtL,
        unsigned short* __restrict__ y16){
  __shared__ __attribute__((aligned(16))) unsigned short sWh[128*128];
  __shared__ __attribute__((aligned(16))) unsigned short sWl[128*128];
  __shared__ __attribute__((aligned(16))) unsigned short sB[4][16*128];
  int t = threadIdx.x;
  for(int f = t; f < 2048; f += 256){
    int colw = f >> 4, kc = f & 15;
    uint4 vh = *(const uint4*)(WtH + colw*128 + kc*8);
    uint4 vl = *(const uint4*)(WtL + colw*128 + kc*8);
    int dst = colw*128 + ((kc ^ (colw & 15)) << 3);
    *(uint4*)&sWh[dst] = vh;
    *(uint4*)&sWl[dst] = vl;
  }
  int lane = t & 63, wid = t >> 6;
  int lg = lane >> 4, lc = lane & 15;
  int rb = blockIdx.x*64 + wid*16;
  int arow = rb + lc;
  int anode = 0;
  if(arow < nrows) anode = MODE ? alist[arow] : arow;
  bf16x8 a_h[4], a_l[4];
  if(MODE){
    const unsigned short* xp = (const unsigned short*)xin_ + (size_t)anode*HH + lg*8;
    #pragma unroll
    for(int kw=0;kw<4;kw++) a_h[kw] = *(const bf16x8*)(xp + kw*32);
  } else {
    const float* xp = (const float*)xin_ + (size_t)anode*HH + lg*8;
    #pragma unroll
    for(int kw=0;kw<4;kw++){
      float4 x0 = *(const float4*)(xp + kw*32);
      float4 x1 = *(const float4*)(xp + kw*32 + 4);
      float xs[8] = {x0.x,x0.y,x0.z,x0.w,x1.x,x1.y,x1.z,x1.w};
      #pragma unroll
      for(int e=0;e<8;e++){
        unsigned hb = bfbits_(xs[e]);
        float hf = __uint_as_float(hb<<16);
        unsigned lb = bfbits_(xs[e]-hf);
        a_h[kw][e] = (short)hb;
        a_l[kw][e] = (short)lb;
      }
    }
  }
  __syncthreads();
  f32x4 acc[8];
  #pragma unroll
  for(int c=0;c<8;c++) acc[c] = (f32x4){0.f,0.f,0.f,0.f};
  #pragma unroll
  for(int kw=0;kw<4;kw++){
    int kch = kw*4 + lg;
    bf16x8 bh[8], bl[8];
    #pragma unroll
    for(int c=0;c<8;c++){
      int idx = (c*16 + lc)*128 + ((kch ^ lc) << 3);
      bh[c] = *(const bf16x8*)&sWh[idx];
      bl[c] = *(const bf16x8*)&sWl[idx];
    }
    #pragma unroll
    for(int c=0;c<8;c++)
      acc[c] = __builtin_amdgcn_mfma_f32_16x16x32_bf16(a_h[kw], bh[c], acc[c], 0,0,0);
    if(MODE){
      #pragma unroll
      for(int c=0;c<8;c++)
        acc[c] = __builtin_amdgcn_mfma_f32_16x16x32_bf16(a_h[kw], bl[c], acc[c], 0,0,0);
    } else {
      #pragma unroll
      for(int c=0;c<8;c++)
        acc[c] = __builtin_amdgcn_mfma_f32_16x16x32_bf16(a_l[kw], bh[c], acc[c], 0,0,0);
      #pragma unroll
      for(int c=0;c<8;c++)
        acc[c] = __builtin_amdgcn_mfma_f32_16x16x32_bf16(a_h[kw], bl[c], acc[c], 0,0,0);
    }
  }
  float s[4];
  #pragma unroll
  for(int r=0;r<4;r++){
    int gr = rb + lg*4 + r;
    float sv = 0.f;
    if(gr < nrows){
      int nd = MODE ? alist[gr] : gr;
      sv = MODE ? dinv[nd]*gate[nd] : dinv[nd];
    }
    s[r] = sv;
  }
  #pragma unroll
  for(int c=0;c<8;c++){
    #pragma unroll
    for(int r=0;r<4;r++)
      sB[wid][(lg*4+r)*128 + c*16 + lc] = (unsigned short)bfbits_(acc[c][r]*s[r]);
  }
  #pragma unroll
  for(int it=0; it<4; it++){
    int row = it*4 + lg;
    int grow = rb + row;
    uint4 v = *(const uint4*)&sB[wid][row*128 + lc*8];
    if(grow < nrows){
      int nd = MODE ? alist[grow] : grow;
      *(uint4*)&y16[(size_t)nd*HH + lc*8] = v;
    }
  }
}

// ---------- aggregate: one wave per node, 4 chunked edge-groups x 16 col-lanes ----------
#define ACCQ(V) do{ \
  f32x2 t0,t1,t2,t3; \
  t0.x=__uint_as_float((V).x<<16); t0.y=__uint_as_float((V).x&0xFFFF0000u); \
  t1.x=__uint_as_float((V).y<<16); t1.y=__uint_as_float((V).y&0xFFFF0000u); \
  t2.x=__uint_as_float((V).z<<16); t2.y=__uint_as_float((V).z&0xFFFF0000u); \
  t3.x=__uint_as_float((V).w<<16); t3.y=__uint_as_float((V).w&0xFFFF0000u); \
  a01+=t0; a23+=t1; a45+=t2; a67+=t3; }while(0)

template<int LIST>
__global__ __launch_bounds__(256) void k_agg(const unsigned short* __restrict__ y16,
        const float* __restrict__ dinv,
        const int* __restrict__ rs, const int* __restrict__ rl,
        const int* __restrict__ col, const int* __restrict__ alist,
        const float* __restrict__ bias, const float* __restrict__ wsc,
        unsigned short* __restrict__ h16, float* __restrict__ p,
        unsigned* __restrict__ hist){
  if(blockIdx.x < 512) hist[blockIdx.x*256 + threadIdx.x] = 0u;
  int w = (blockIdx.x*256 + threadIdx.x) >> 6;
  int lane = threadIdx.x & 63;
  int g = lane >> 4, c = lane & 15;
  int node = LIST ? alist[w] : w;
  float di = dinv[node];
  int e0 = rs[node], len = rl[node];
  const char* yb = (const char*)y16;
  unsigned lc16 = (unsigned)(c << 4);
  int chunk = (len + 3) >> 2;
  int ib = g*chunk;
  int ie = ib + chunk; if(ie > len) ie = len;
  f32x2 a01 = {0.f,0.f}, a23 = {0.f,0.f}, a45 = {0.f,0.f}, a67 = {0.f,0.f};
  const int* ce = col + e0;
  int i = ib;
  for(; i+3 < ie; i += 4){
    int c0 = ce[i], c1 = ce[i+1], c2 = ce[i+2], c3 = ce[i+3];
    uint4 v0 = *(const uint4*)(yb + (((unsigned)c0<<8) | lc16));
    uint4 v1 = *(const uint4*)(yb + (((unsigned)c1<<8) | lc16));
    uint4 v2 = *(const uint4*)(yb + (((unsigned)c2<<8) | lc16));
    uint4 v3 = *(const uint4*)(yb + (((unsigned)c3<<8) | lc16));
    ACCQ(v0); ACCQ(v1); ACCQ(v2); ACCQ(v3);
  }
  for(; i < ie; i++){
    int c0 = ce[i];
    uint4 v0 = *(const uint4*)(yb + (((unsigned)c0<<8) | lc16));
    ACCQ(v0);
  }
  float a0=a01.x, a1=a01.y, a2=a23.x, a3=a23.y, a4=a45.x, a5=a45.y, a6=a67.x, a7=a67.y;
  a0 += __shfl_xor(a0,16,64); a0 += __shfl_xor(a0,32,64);
  a1 += __shfl_xor(a1,16,64); a1 += __shfl_xor(a1,32,64);
  a2 += __shfl_xor(a2,16,64); a2 += __shfl_xor(a2,32,64);
  a3 += __shfl_xor(a3,16,64); a3 += __shfl_xor(a3,32,64);
  a4 += __shfl_xor(a4,16,64); a4 += __shfl_xor(a4,32,64);
  a5 += __shfl_xor(a5,16,64); a5 += __shfl_xor(a5,32,64);
  a6 += __shfl_xor(a6,16,64); a6 += __shfl_xor(a6,32,64);
  a7 += __shfl_xor(a7,16,64); a7 += __shfl_xor(a7,32,64);
  uint4 sv = *(const uint4*)(yb + (((unsigned)node<<8) | lc16));
  const float4* b4 = (const float4*)bias;
  float4 bb0 = b4[2*c], bb1 = b4[2*c+1];
  float o0 = fmaxf(fmaf(di, a0 + bflo_(sv.x), bb0.x), 0.f);
  float o1 = fmaxf(fmaf(di, a1 + bfhi_(sv.x), bb0.y), 0.f);
  float o2 = fmaxf(fmaf(di, a2 + bflo_(sv.y), bb0.z), 0.f);
  float o3 = fmaxf(fmaf(di, a3 + bfhi_(sv.y), bb0.w), 0.f);
  float o4 = fmaxf(fmaf(di, a4 + bflo_(sv.z), bb1.x), 0.f);
  float o5 = fmaxf(fmaf(di, a5 + bfhi_(sv.z), bb1.y), 0.f);
  float o6 = fmaxf(fmaf(di, a6 + bflo_(sv.w), bb1.z), 0.f);
  float o7 = fmaxf(fmaf(di, a7 + bfhi_(sv.w), bb1.w), 0.f);
  if(g == 0){
    uint4 o;
    o.x = bfpack_(o0,o1); o.y = bfpack_(o2,o3);
    o.z = bfpack_(o4,o5); o.w = bfpack_(o6,o7);
    ((uint4*)(h16 + (size_t)node*HH))[c] = o;
  }
  const float4* w4 = (const float4*)wsc;
  float4 w0 = w4[2*c], w1 = w4[2*c+1];
  float pp = o0*w0.x + o1*w0.y + o2*w0.z + o3*w0.w
           + o4*w1.x + o5*w1.y + o6*w1.z + o7*w1.w;
  pp += __shfl_xor(pp, 1, 64);
  pp += __shfl_xor(pp, 2, 64);
  pp += __shfl_xor(pp, 4, 64);
  pp += __shfl_xor(pp, 8, 64);
  if(lane == 0) p[node] = di*pp;
}

// ---------- score + fused hi-histogram ----------
template<int LIST>
__global__ void k_score(const float* __restrict__ p, const float* __restrict__ dinv,
                        const int* __restrict__ rs, const int* __restrict__ rl,
                        const int* __restrict__ col, const int* __restrict__ alist, int n,
                        const float* __restrict__ bs, float* __restrict__ score,
                        unsigned* __restrict__ key, unsigned* __restrict__ hist){
  int w = blockIdx.x*256 + threadIdx.x;
  if(w >= n) return;
  int i = LIST ? alist[w] : w;
  float di = dinv[i];
  float s = 0.f;
  int e0 = rs[i], len = rl[i];
  const int* ce = col + e0;
  int e = 0;
  for(; e+3 < len; e += 4){
    int c0 = ce[e], c1 = ce[e+1], c2 = ce[e+2], c3 = ce[e+3];
    s += (p[c0] + p[c1]) + (p[c2] + p[c3]);
  }
  for(; e < len; e++) s += p[ce[e]];
  float sc = di*(s + p[i]) + bs[0];
  score[i] = sc;
  unsigned kv = fsort_(sc);
  key[i] = kv;
  atomicAdd(&hist[kv>>16], 1u);
}

// ---------- radix select ----------
__global__ void k_hist_lo(const unsigned* __restrict__ key, const unsigned* __restrict__ state,
                          unsigned* __restrict__ histB){
  int i = blockIdx.x*256 + threadIdx.x;
  if(i < NN){
    unsigned kv = key[i];
    if((kv >> 16) == state[0]) atomicAdd(&histB[kv & 0xFFFFu], 1u);
  }
}
__global__ void k_pick(const unsigned* __restrict__ hist, unsigned* __restrict__ state,
                       int k_in, int mode){
  __shared__ unsigned csum[256];
  __shared__ unsigned vrow[256];
  __shared__ int rowSh;
  __shared__ unsigned aboveSh;
  int t = threadIdx.x;
  const uint4* h4 = (const uint4*)(hist + t*256);
  unsigned s = 0;
  for(int j=0;j<64;j++){ uint4 v = h4[j]; s += v.x+v.y+v.z+v.w; }
  csum[t] = s;
  if(t == 0) rowSh = -1;
  __syncthreads();
  for(int off=1; off<256; off<<=1){
    unsigned v = (t+off < 256) ? csum[t+off] : 0u;
    __syncthreads();
    csum[t] += v;
    __syncthreads();
  }
  unsigned k = (mode == 0) ? (unsigned)k_in : state[1];
  unsigned above = csum[t] - s;
  if(above < k && above + s >= k){ rowSh = t; aboveSh = above; }
  __syncthreads();
  int row = rowSh;
  if(row >= 0){
    vrow[t] = hist[row*256 + t];
    __syncthreads();
    for(int off=1; off<256; off<<=1){
      unsigned u = (t+off < 256) ? vrow[t+off] : 0u;
      __syncthreads();
      vrow[t] += u;
      __syncthreads();
    }
    unsigned above2 = aboveSh;
    unsigned sincl = vrow[t];
    unsigned snext = (t < 255) ? vrow[t+1] : 0u;
    bool cond  = (above2 + sincl >= k);
    bool condn = (above2 + snext >= k);
    if(cond && !condn){
      unsigned run = above2 + snext;
      if(mode == 0){ state[0] = (unsigned)(row*256+t); state[1] = k - run; }
      else { state[2] = (state[0] << 16) | (unsigned)(row*256+t); state[3] = k - run; }
    }
  }
}

// ---------- mask + gate + alive-list + select-bitmask + fused readout partials ----------
__global__ __launch_bounds__(256) void k_maskCR(unsigned* __restrict__ key,
        const float* __restrict__ score, const unsigned* __restrict__ state,
        const unsigned short* __restrict__ h16,
        unsigned* __restrict__ selb, float* __restrict__ gate,
        int* __restrict__ alist_out, unsigned* __restrict__ acounter,
        float* __restrict__ rpart, int slotbase){
  __shared__ int wcnt[4];
  __shared__ int priorSh;
  __shared__ int redi[256];
  __shared__ float gl[256];
  __shared__ unsigned char slf[256];
  __shared__ float4 red[256];
  __shared__ float out2[256];
  int t = threadIdx.x;
  int i = blockIdx.x*256 + t;
  unsigned T = state[2];
  int trem = (int)state[3];
  unsigned kv = (i < NN) ? key[i] : 0u;
  bool match = (kv == T);
  unsigned long long m = __ballot(match);
  int lane = t & 63, wid = t >> 6;
  if(lane == 0) wcnt[wid] = __popcll(m);
  if(t == 0) priorSh = 0;
  __syncthreads();
  int hasMatch = wcnt[0] | wcnt[1] | wcnt[2] | wcnt[3];
  int bbase = blockIdx.x*256;
  if(hasMatch){
    int cm = 0;
    for(int j = t*4; j < bbase; j += 1024){
      uint4 kk = *(const uint4*)&key[j];
      cm += (kk.x==T) + (kk.y==T) + (kk.z==T) + (kk.w==T);
    }
    redi[t] = cm;
    __syncthreads();
    for(int off=128; off>0; off>>=1){
      if(t < off) redi[t] += redi[t+off];
      __syncthreads();
    }
    if(t == 0) priorSh = redi[0];
    __syncthreads();
  }
  int pre = 0;
  for(int w=0; w<wid; w++) pre += wcnt[w];
  int lrank = __popcll(m & ((1ull << lane) - 1ull));
  int rank = priorSh + pre + lrank;
  bool sel = (kv > T) || (match && rank < trem);
  float gg = sel ? tanhf(score[i]) : 0.f;
  gl[t] = gg;
  slf[t] = sel ? 1 : 0;
  if(i < NN){
    gate[i] = gg;
    if(!sel) key[i] = 0u;
  }
  unsigned long long sm = __ballot(sel);
  if(lane == 0){
    int widx = blockIdx.x*4 + wid;
    selb[widx*2]   = (unsigned)sm;
    selb[widx*2+1] = (unsigned)(sm >> 32);
  }
  unsigned abase = 0;
  if(lane == 0) abase = atomicAdd(acounter, (unsigned)__popcll(sm));
  abase = (unsigned)__shfl((int)abase, 0, 64);
  if(sel) alist_out[abase + __popcll(sm & ((1ull << lane) - 1ull))] = i;
  __syncthreads();
  int ch = t & 15;
  int slot = t >> 4;
  float mm[8] = {0,0,0,0,0,0,0,0};
  float MM[8] = {-1e30f,-1e30f,-1e30f,-1e30f,-1e30f,-1e30f,-1e30f,-1e30f};
  for(int itr=0; itr<16; itr++){
    int nl = slot + itr*16;
    int node = bbase + nl;
    if(node < NN && slf[nl]){
      float g = gl[nl];
      uint4 v = ((const uint4*)(h16 + (size_t)node*HH))[ch];
      float x0 = g*bflo_(v.x), x1 = g*bfhi_(v.x);
      float x2 = g*bflo_(v.y), x3 = g*bfhi_(v.y);
      float x4 = g*bflo_(v.z), x5 = g*bfhi_(v.z);
      float x6 = g*bflo_(v.w), x7 = g*bfhi_(v.w);
      mm[0]+=x0; mm[1]+=x1; mm[2]+=x2; mm[3]+=x3;
      mm[4]+=x4; mm[5]+=x5; mm[6]+=x6; mm[7]+=x7;
      MM[0]=fmaxf(MM[0],x0); MM[1]=fmaxf(MM[1],x1); MM[2]=fmaxf(MM[2],x2); MM[3]=fmaxf(MM[3],x3);
      MM[4]=fmaxf(MM[4],x4); MM[5]=fmaxf(MM[5],x5); MM[6]=fmaxf(MM[6],x6); MM[7]=fmaxf(MM[7],x7);
    }
  }
  #pragma unroll
  for(int half=0; half<2; half++){
    red[t] = make_float4(mm[half*4+0],mm[half*4+1],mm[half*4+2],mm[half*4+3]);
    __syncthreads();
    if(t < 16){
      float4 sacc = red[t];
      for(int j=1;j<16;j++){
        float4 o = red[t + 16*j];
        sacc.x += o.x; sacc.y += o.y; sacc.z += o.z; sacc.w += o.w;
      }
      int d = t*8 + half*4;
      out2[d+0] = sacc.x; out2[d+1] = sacc.y; out2[d+2] = sacc.z; out2[d+3] = sacc.w;
    }
    __syncthreads();
    red[t] = make_float4(MM[half*4+0],MM[half*4+1],MM[half*4+2],MM[half*4+3]);
    __syncthreads();
    if(t < 16){
      float4 sacc = red[t];
      for(int j=1;j<16;j++){
        float4 o = red[t + 16*j];
        sacc.x = fmaxf(sacc.x,o.x); sacc.y = fmaxf(sacc.y,o.y);
        sacc.z = fmaxf(sacc.z,o.z); sacc.w = fmaxf(sacc.w,o.w);
      }
      int d = 128 + t*8 + half*4;
      out2[d+0] = sacc.x; out2[d+1] = sacc.y; out2[d+2] = sacc.z; out2[d+3] = sacc.w;
    }
    __syncthreads();
  }
  rpart[(size_t)(slotbase + blockIdx.x)*256 + t] = out2[t];
}

// ---------- parallel edge compaction: bitmask select, 16 lanes/node ----------
__global__ __launch_bounds__(256) void k_compact(const int* __restrict__ alist, int n,
        const unsigned* __restrict__ selb,
        const int* __restrict__ rs_old, const int* __restrict__ rl_old,
        const int* __restrict__ col_old,
        int* __restrict__ rs_new, int* __restrict__ rl_new, int* __restrict__ col_new,
        float* __restrict__ dinv, unsigned* __restrict__ ecnt){
  __shared__ unsigned gcnt[16];
  __shared__ unsigned gbase[16];
  __shared__ unsigned blkbase;
  int t = threadIdx.x;
  int g = t >> 4, lane = t & 15;
  int gsh = ((t >> 4) & 3) * 16;
  int idx = blockIdx.x*16 + g;
  int node = -1, e0 = 0, len = 0;
  if(idx < n){ node = alist[idx]; e0 = rs_old[node]; len = rl_old[node]; }
  int cnt = 0;
  for(int i=lane; i<len; i+=16){
    int s = col_old[e0+i];
    cnt += (int)((selb[s>>5] >> (s&31)) & 1u);
  }
  cnt += __shfl_xor(cnt,1,64); cnt += __shfl_xor(cnt,2,64);
  cnt += __shfl_xor(cnt,4,64); cnt += __shfl_xor(cnt,8,64);
  if(lane == 0) gcnt[g] = (node >= 0) ? (unsigned)cnt : 0u;
  __syncthreads();
  if(t == 0){
    unsigned s = 0;
    for(int j=0;j<16;j++){ gbase[j] = s; s += gcnt[j]; }
    blkbase = s ? atomicAdd(ecnt, s) : 0u;
  }
  __syncthreads();
  unsigned base = blkbase + gbase[g];
  if(node >= 0 && lane == 0){
    rs_new[node] = (int)base;
    rl_new[node] = cnt;
    dinv[node] = rsqrtf(1.f + (float)cnt);
  }
  int pos = (int)base;
  for(int i0=0; i0<len; i0+=16){
    int i = i0 + lane;
    bool keep = false; int s = 0;
    if(i < len){ s = col_old[e0+i]; keep = ((selb[s>>5] >> (s&31)) & 1u) != 0u; }
    unsigned long long b = __ballot(keep);
    unsigned gb = (unsigned)((b >> gsh) & 0xFFFFull);
    int rank = __popc(gb & ((1u << lane) - 1u));
    if(keep) col_new[pos + rank] = s;
    pos += __popc(gb);
  }
}

// ---------- parallel reduce of readout partials: 48 blocks ----------
__global__ void k_red(const float* __restrict__ rpart, float* __restrict__ rpart2){
  int l = blockIdx.x >> 4, c = blockIdx.x & 15;
  int t = threadIdx.x;
  int j0 = c*SPC, j1 = j0 + SPC; if(j1 > NB_N) j1 = NB_N;
  const float* rp = rpart + (size_t)l*NB_N*256;
  float r;
  if(t < 128){
    float s0=0.f,s1=0.f,s2=0.f,s3=0.f;
    int j = j0;
    for(; j+3 < j1; j += 4){
      s0 += rp[(size_t)(j  )*256 + t];
      s1 += rp[(size_t)(j+1)*256 + t];
      s2 += rp[(size_t)(j+2)*256 + t];
      s3 += rp[(size_t)(j+3)*256 + t];
    }
    for(; j < j1; j++) s0 += rp[(size_t)j*256 + t];
    r = (s0+s1)+(s2+s3);
  } else {
    float m0=-1e30f,m1=-1e30f,m2=-1e30f,m3=-1e30f;
    int j = j0;
    for(; j+3 < j1; j += 4){
      m0 = fmaxf(m0, rp[(size_t)(j  )*256 + t]);
      m1 = fmaxf(m1, rp[(size_t)(j+1)*256 + t]);
      m2 = fmaxf(m2, rp[(size_t)(j+2)*256 + t]);
      m3 = fmaxf(m3, rp[(size_t)(j+3)*256 + t]);
    }
    for(; j < j1; j++) m0 = fmaxf(m0, rp[(size_t)j*256 + t]);
    r = fmaxf(fmaxf(m0,m1), fmaxf(m2,m3));
  }
  rpart2[(size_t)blockIdx.x*256 + t] = r;
}

// ---------- final reduce (48 chunk-partials) + MLP head + log_softmax ----------
__global__ void k_mlp(const float* __restrict__ rpart2,
                      const float* __restrict__ M1, const float* __restrict__ bm1,
                      const float* __restrict__ M2, const float* __restrict__ bm2,
                      const float* __restrict__ M3, const float* __restrict__ bm3,
                      float* __restrict__ out){
  __shared__ float R[256];
  __shared__ float y1[128];
  __shared__ float y2[64];
  __shared__ float y3[16];
  int t = threadIdx.x;
  const float kinv[3] = {1.f/50000.f, 1.f/25000.f, 1.f/12500.f};
  if(t < 128){
    float acc = 0.f;
    for(int l=0; l<3; l++){
      float s = 0.f;
      #pragma unroll
      for(int c=0; c<NCH; c++) s += rpart2[(size_t)(l*NCH+c)*256 + t];
      acc += s * kinv[l];
    }
    R[t] = acc;
  } else {
    float acc = 0.f;
    for(int l=0; l<3; l++){
      float m = -1e30f;
      #pragma unroll
      for(int c=0; c<NCH; c++) m = fmaxf(m, rpart2[(size_t)(l*NCH+c)*256 + t]);
      acc += m;
    }
    R[t] = acc;
  }
  __syncthreads();
  if(t < 128){
    float a = bm1[t];
    for(int d=0; d<256; d++) a += R[d]*M1[d*128+t];
    y1[t] = fmaxf(a, 0.f);
  }
  __syncthreads();
  if(t < 64){
    float a = bm2[t];
    for(int d=0; d<128; d++) a += y1[d]*M2[d*64+t];
    y2[t] = fmaxf(a, 0.f);
  }
  __syncthreads();
  if(t < 10){
    float a = bm3[t];
    for(int d=0; d<64; d++) a += y2[d]*M3[d*10+t];
    y3[t] = a;
  }
  __syncthreads();
  if(t == 0){
    float mx = -1e30f;
    for(int o=0;o<10;o++) mx = fmaxf(mx, y3[o]);
    float s = 0.f;
    for(int o=0;o<10;o++) s += expf(y3[o]-mx);
    float ls = logf(s);
    for(int o=0;o<10;o++) out[o] = y3[o] - mx - ls;
  }
}

extern "C" void kernel_launch(void* const* d_in, const int* in_sizes, int n_in,
                              void* d_out, int out_size, void* d_ws, size_t ws_size,
                              hipStream_t stream){
  (void)in_sizes; (void)n_in; (void)out_size; (void)ws_size;
  const float* x  = (const float*)d_in[0];
  const int*   ei = (const int*)d_in[1];
  const float* W[3]   = {(const float*)d_in[2],  (const float*)d_in[6],  (const float*)d_in[10]};
  const float* bb[3]  = {(const float*)d_in[3],  (const float*)d_in[7],  (const float*)d_in[11]};
  const float* wsc[3] = {(const float*)d_in[4],  (const float*)d_in[8],  (const float*)d_in[12]};
  const float* bsc[3] = {(const float*)d_in[5],  (const float*)d_in[9],  (const float*)d_in[13]};
  const float* M1  = (const float*)d_in[14];
  const float* bm1 = (const float*)d_in[15];
  const float* M2  = (const float*)d_in[16];
  const float* bm2 = (const float*)d_in[17];
  const float* M3  = (const float*)d_in[18];
  const float* bm3 = (const float*)d_in[19];
  float* out = (float*)d_out;

  char* base = (char*)d_ws;
  size_t off = 0;
  auto alloc = [&](size_t bytes)->char*{
    char* ptr = base + off;
    off += (bytes + 511) & ~(size_t)511;
    return ptr;
  };
  unsigned short* y16  = (unsigned short*)alloc((size_t)NN*HH*2);
  unsigned short* h16  = (unsigned short*)alloc((size_t)NN*HH*2);
  int*      col0      = (int*)     alloc((size_t)EE*4);
  int*      col1      = (int*)     alloc((size_t)EE*4);
  int*      col2      = (int*)     alloc((size_t)EE*4);
  unsigned* staging   = (unsigned*)alloc((size_t)NBKT*CAP*4);
  int*      rs0       = (int*)     alloc((size_t)NN*4);
  int*      rl0       = (int*)     alloc((size_t)NN*4);
  int*      rs1       = (int*)     alloc((size_t)NN*4);
  int*      rl1       = (int*)     alloc((size_t)NN*4);
  int*      rs2       = (int*)     alloc((size_t)NN*4);
  int*      rl2       = (int*)     alloc((size_t)NN*4);
  float*    dinv      = (float*)   alloc((size_t)NN*4);
  float*    pbuf      = (float*)   alloc((size_t)NN*4);
  float*    score     = (float*)   alloc((size_t)NN*4);
  float*    gate      = (float*)   alloc((size_t)NN*4);
  unsigned* key       = (unsigned*)alloc((size_t)NN*4);
  unsigned* selb      = (unsigned*)alloc((size_t)3200*4);
  int*      alistA    = (int*)     alloc((size_t)50000*4);
  int*      alistB    = (int*)     alloc((size_t)25000*4);
  unsigned* hist      = (unsigned*)alloc((size_t)2*65536*4);
  unsigned* bktcnt    = (unsigned*)alloc((size_t)(NBKT+1)*4);
  unsigned* state     = (unsigned*)alloc(256);
  float*    rpart     = (float*)   alloc((size_t)3*NB_N*256*4);
  float*    rpart2    = (float*)   alloc((size_t)3*NCH*256*4);
  unsigned short* WtH = (unsigned short*)alloc((size_t)3*16384*2);
  unsigned short* WtL = (unsigned short*)alloc((size_t)3*16384*2);

  // CSR build + W prep
  k_init<<<4,256,0,stream>>>(ei, state, bktcnt, W[0], W[1], W[2], WtH, WtL);
  k_binA<<<NBKT,256,0,stream>>>(ei, state, bktcnt, staging);
  k_binB<<<NBKT,256,0,stream>>>(staging, bktcnt, rs0, rl0, col0, dinv);

  // ---- layer 1 (identity rows: all 100000 alive) ----
  k_gemmM<0><<<1563,256,0,stream>>>(x, nullptr, dinv, nullptr, NN, WtH, WtL, y16);
  k_agg<0><<<25000,256,0,stream>>>(y16, dinv, rs0, rl0, col0, nullptr, bb[0], wsc[0], h16, pbuf, hist);
  k_score<0><<<NB_N,256,0,stream>>>(pbuf, dinv, rs0, rl0, col0, nullptr, NN, bsc[0], score, key, hist);
  k_pick<<<1,256,0,stream>>>(hist, state, 50000, 0);
  k_hist_lo<<<NB_N,256,0,stream>>>(key, state, hist + 65536);
  k_pick<<<1,256,0,stream>>>(hist + 65536, state, 0, 1);
  k_maskCR<<<NB_N,256,0,stream>>>(key, score, state, h16, selb, gate, alistA, state+12, rpart, 0);
  k_compact<<<3125,256,0,stream>>>(alistA, 50000, selb, rs0, rl0, col0, rs1, rl1, col1, dinv, state+16);

  // ---- layer 2 (50000 alive) ----
  k_gemmM<1><<<782,256,0,stream>>>(h16, gate, dinv, alistA, 50000, WtH+16384, WtL+16384, y16);
  k_agg<1><<<12500,256,0,stream>>>(y16, dinv, rs1, rl1, col1, alistA, bb[1], wsc[1], h16, pbuf, hist);
  k_score<1><<<196,256,0,stream>>>(pbuf, dinv, rs1, rl1, col1, alistA, 50000, bsc[1], score, key, hist);
  k_pick<<<1,256,0,stream>>>(hist, state, 25000, 0);
  k_hist_lo<<<NB_N,256,0,stream>>>(key, state, hist + 65536);
  k_pick<<<1,256,0,stream>>>(hist + 65536, state, 0, 1);
  k_maskCR<<<NB_N,256,0,stream>>>(key, score, state, h16, selb, gate, alistB, state+13, rpart, NB_N);
  k_compact<<<1563,256,0,stream>>>(alistB, 25000, selb, rs1, rl1, col1, rs2, rl2, col2, dinv, state+17);

  // ---- layer 3 (25000 alive) ----
  k_gemmM<1><<<391,256,0,stream>>>(h16, gate, dinv, alistB, 25000, WtH+2*16384, WtL+2*16384, y16);
  k_agg<1><<<6250,256,0,stream>>>(y16, dinv, rs2, rl2, col2, alistB, bb[2], wsc[2], h16, pbuf, hist);
  k_score<1><<<98,256,0,stream>>>(pbuf, dinv, rs2, rl2, col2, alistB, 25000, bsc[2], score, key, hist);
  k_pick<<<1,256,0,stream>>>(hist, state, 12500, 0);
  k_hist_lo<<<NB_N,256,0,stream>>>(key, state, hist + 65536);
  k_pick<<<1,256,0,stream>>>(hist + 65536, state, 0, 1);
  k_maskCR<<<NB_N,256,0,stream>>>(key, score, state, h16, selb, gate, alistA, state+14, rpart, 2*NB_N);

  k_red<<<3*NCH,256,0,stream>>>(rpart, rpart2);
  k_mlp<<<1,256,0,stream>>>(rpart2, M1, bm1, M2, bm2, M3, bm3, out);
}